// Round 1
// baseline (1060.579 us; speedup 1.0000x reference)
//
#include <hip/hip_runtime.h>
#include <hip/hip_bf16.h>

#define NN 100000
#define NE 1600000
#define NG 512
#define NC 10

// ---------------- preprocessing: degree, dinv, CSR by dst ----------------

__global__ __launch_bounds__(256) void k_deg(const int* __restrict__ dst, int* __restrict__ deg) {
  int e = blockIdx.x * 256 + threadIdx.x;
  if (e < NE) atomicAdd(&deg[dst[e]], 1);
}

__global__ __launch_bounds__(256) void k_dinv(const int* __restrict__ deg, float* __restrict__ dinv) {
  int i = blockIdx.x * 256 + threadIdx.x;
  if (i < NN) dinv[i] = rsqrtf((float)deg[i] + 1.0f);
}

__global__ __launch_bounds__(256) void k_bsum(const int* __restrict__ deg, int* __restrict__ bsum) {
  __shared__ int sm[256];
  int i = blockIdx.x * 256 + threadIdx.x;
  sm[threadIdx.x] = (i < NN) ? deg[i] : 0;
  __syncthreads();
  for (int o = 128; o > 0; o >>= 1) {
    if (threadIdx.x < o) sm[threadIdx.x] += sm[threadIdx.x + o];
    __syncthreads();
  }
  if (threadIdx.x == 0) bsum[blockIdx.x] = sm[0];
}

__global__ void k_scan_bsum(int* bsum, int nb) {
  if (threadIdx.x == 0 && blockIdx.x == 0) {
    int run = 0;
    for (int b = 0; b < nb; ++b) { int v = bsum[b]; bsum[b] = run; run += v; }
  }
}

__global__ __launch_bounds__(256) void k_offs(const int* __restrict__ deg, const int* __restrict__ bsum,
                                              int* __restrict__ offs) {
  __shared__ int sm[256];
  int i = blockIdx.x * 256 + threadIdx.x;
  int v = (i < NN) ? deg[i] : 0;
  sm[threadIdx.x] = v;
  __syncthreads();
  for (int o = 1; o < 256; o <<= 1) {
    int t = (threadIdx.x >= o) ? sm[threadIdx.x - o] : 0;
    __syncthreads();
    sm[threadIdx.x] += t;
    __syncthreads();
  }
  if (i < NN) offs[i] = bsum[blockIdx.x] + sm[threadIdx.x] - v;  // exclusive
}

__global__ __launch_bounds__(256) void k_csr(const int* __restrict__ src, const int* __restrict__ dst,
                                             const int* __restrict__ offs, int* __restrict__ cursor,
                                             const float* __restrict__ dinv,
                                             int* __restrict__ csr_src, float* __restrict__ csr_norm) {
  int e = blockIdx.x * 256 + threadIdx.x;
  if (e < NE) {
    int s = src[e], d = dst[e];
    int p = offs[d] + atomicAdd(&cursor[d], 1);
    csr_src[p] = s;
    csr_norm[p] = dinv[s] * dinv[d];
  }
}

// ---------------- f32 GEMM: Out[M,128] = A[M,128] @ W[128,128] (+bias)(+relu) ----------------
// 256 threads, 128-row tile, 8x8 register blocking. W + swizzled X in LDS (128 KB).

__global__ __launch_bounds__(256) void k_gemm(const float* __restrict__ A, const float* __restrict__ W,
                                              const float* __restrict__ bias, float* __restrict__ Out,
                                              int M, int addBias, int doRelu) {
  __shared__ float4 Wl[128 * 32];
  __shared__ float4 Xl[128 * 32];
  const float4* W4 = (const float4*)W;
  for (int i = threadIdx.x; i < 4096; i += 256) Wl[i] = W4[i];
  int row0 = blockIdx.x * 128;
  const float4* A4 = (const float4*)A;
  for (int i = threadIdx.x; i < 4096; i += 256) {
    int r = i >> 5, g = i & 31;
    int gr = row0 + r;
    float4 v = make_float4(0.f, 0.f, 0.f, 0.f);
    if (gr < M) v = A4[gr * 32 + g];
    Xl[r * 32 + (g ^ ((r >> 3) & 7))] = v;   // granule XOR swizzle: spreads rows across banks
  }
  __syncthreads();

  int cg = threadIdx.x & 15;   // col group: 8 cols
  int rg = threadIdx.x >> 4;   // row group: 8 rows
  int swz = rg & 7;
  float acc[8][8] = {};

  for (int g = 0; g < 32; ++g) {
    float4 xv[8];
#pragma unroll
    for (int i = 0; i < 8; ++i) xv[i] = Xl[(rg * 8 + i) * 32 + (g ^ swz)];
#pragma unroll
    for (int kk = 0; kk < 4; ++kk) {
      float4 wa = Wl[(g * 4 + kk) * 32 + cg * 2];
      float4 wb = Wl[(g * 4 + kk) * 32 + cg * 2 + 1];
#pragma unroll
      for (int i = 0; i < 8; ++i) {
        float x = (kk == 0) ? xv[i].x : (kk == 1) ? xv[i].y : (kk == 2) ? xv[i].z : xv[i].w;
        acc[i][0] = fmaf(x, wa.x, acc[i][0]);
        acc[i][1] = fmaf(x, wa.y, acc[i][1]);
        acc[i][2] = fmaf(x, wa.z, acc[i][2]);
        acc[i][3] = fmaf(x, wa.w, acc[i][3]);
        acc[i][4] = fmaf(x, wb.x, acc[i][4]);
        acc[i][5] = fmaf(x, wb.y, acc[i][5]);
        acc[i][6] = fmaf(x, wb.z, acc[i][6]);
        acc[i][7] = fmaf(x, wb.w, acc[i][7]);
      }
    }
  }

  float4 ba = make_float4(0.f, 0.f, 0.f, 0.f), bb = ba;
  if (addBias) {
    ba = ((const float4*)bias)[cg * 2];
    bb = ((const float4*)bias)[cg * 2 + 1];
  }
#pragma unroll
  for (int i = 0; i < 8; ++i) {
    int gr = row0 + rg * 8 + i;
    if (gr < M) {
      float4 oa, ob;
      oa.x = acc[i][0] + ba.x; oa.y = acc[i][1] + ba.y; oa.z = acc[i][2] + ba.z; oa.w = acc[i][3] + ba.w;
      ob.x = acc[i][4] + bb.x; ob.y = acc[i][5] + bb.y; ob.z = acc[i][6] + bb.z; ob.w = acc[i][7] + bb.w;
      if (doRelu) {
        oa.x = fmaxf(oa.x, 0.f); oa.y = fmaxf(oa.y, 0.f); oa.z = fmaxf(oa.z, 0.f); oa.w = fmaxf(oa.w, 0.f);
        ob.x = fmaxf(ob.x, 0.f); ob.y = fmaxf(ob.y, 0.f); ob.z = fmaxf(ob.z, 0.f); ob.w = fmaxf(ob.w, 0.f);
      }
      ((float4*)Out)[gr * 32 + cg * 2] = oa;
      ((float4*)Out)[gr * 32 + cg * 2 + 1] = ob;
    }
  }
}

// ---------------- edge aggregation: wave per node, float2 per lane ----------------
// out[i,:] = sum_{e: dst=i} hp[src_e,:] * dinv[src]*dinv[i]  +  hp[i,:]*dinv[i]^2  + b  (relu)

__global__ __launch_bounds__(256) void k_agg(const float* __restrict__ hp, const int* __restrict__ offs,
                                             const int* __restrict__ deg, const float* __restrict__ dinv,
                                             const int* __restrict__ csr_src, const float* __restrict__ csr_norm,
                                             const float* __restrict__ bias, float* __restrict__ out, int doRelu) {
  int node = blockIdx.x * 4 + (threadIdx.x >> 6);
  if (node >= NN) return;
  int l = threadIdx.x & 63;
  const float2* hp2 = (const float2*)hp;
  float di = dinv[node];
  float2 v = hp2[node * 64 + l];
  float2 acc = make_float2(v.x * di * di, v.y * di * di);
  int p0 = offs[node], n = deg[node];
  int p = 0;
  for (; p + 2 <= n; p += 2) {
    int s0 = csr_src[p0 + p], s1 = csr_src[p0 + p + 1];
    float w0 = csr_norm[p0 + p], w1 = csr_norm[p0 + p + 1];
    float2 a = hp2[s0 * 64 + l];
    float2 b = hp2[s1 * 64 + l];
    acc.x += a.x * w0 + b.x * w1;
    acc.y += a.y * w0 + b.y * w1;
  }
  if (p < n) {
    int s0 = csr_src[p0 + p];
    float w0 = csr_norm[p0 + p];
    float2 a = hp2[s0 * 64 + l];
    acc.x += a.x * w0;
    acc.y += a.y * w0;
  }
  float2 b2 = ((const float2*)bias)[l];
  acc.x += b2.x;
  acc.y += b2.y;
  if (doRelu) { acc.x = fmaxf(acc.x, 0.f); acc.y = fmaxf(acc.y, 0.f); }
  ((float2*)out)[node * 64 + l] = acc;
}

// ---------------- pooling over sorted batch + classifier ----------------

__device__ __forceinline__ int lowerb(const int* a, int n, int key) {
  int lo = 0, hi = n;
  while (lo < hi) {
    int mid = (lo + hi) >> 1;
    if (a[mid] < key) lo = mid + 1; else hi = mid;
  }
  return lo;
}

__global__ __launch_bounds__(128) void k_pool(const float* __restrict__ h, const int* __restrict__ batch,
                                              float* __restrict__ g) {
  int gi = blockIdx.x, d = threadIdx.x;
  int lo = lowerb(batch, NN, gi), hi = lowerb(batch, NN, gi + 1);
  float acc = 0.f;
  for (int i = lo; i < hi; ++i) acc += h[i * 128 + d];
  g[gi * 128 + d] = acc;
}

__global__ __launch_bounds__(128) void k_cls(const float* __restrict__ t, const float* __restrict__ Wr2,
                                             const float* __restrict__ br2, float* __restrict__ out) {
  int gi = blockIdx.x;
  __shared__ float row[128];
  row[threadIdx.x] = t[gi * 128 + threadIdx.x];
  __syncthreads();
  if (threadIdx.x < NC) {
    float acc = br2[threadIdx.x];
    for (int k = 0; k < 128; ++k) acc = fmaf(row[k], Wr2[k * NC + threadIdx.x], acc);
    out[gi * NC + threadIdx.x] = acc;
  }
}

// ---------------- launch ----------------

extern "C" void kernel_launch(void* const* d_in, const int* in_sizes, int n_in,
                              void* d_out, int out_size, void* d_ws, size_t ws_size,
                              hipStream_t stream) {
  const float* x     = (const float*)d_in[0];
  const int*   src   = (const int*)d_in[1];   // c_2
  const int*   dst   = (const int*)d_in[2];   // u_2
  const int*   batch = (const int*)d_in[3];
  const float* W_enc = (const float*)d_in[4];
  const float* b_enc = (const float*)d_in[5];
  const float* W1 = (const float*)d_in[6],  *b1 = (const float*)d_in[7];
  const float* W2 = (const float*)d_in[8],  *b2 = (const float*)d_in[9];
  const float* W3 = (const float*)d_in[10], *b3 = (const float*)d_in[11];
  const float* Wr1 = (const float*)d_in[12], *br1 = (const float*)d_in[13];
  const float* Wr2 = (const float*)d_in[14], *br2 = (const float*)d_in[15];
  float* out = (float*)d_out;

  char* ws = (char*)d_ws;
  size_t off = 0;
  auto alloc = [&](size_t bytes) {
    void* p = ws + off;
    off = (off + bytes + 255) & ~(size_t)255;
    return p;
  };
  float* h        = (float*)alloc((size_t)NN * 128 * 4);
  float* hp       = (float*)alloc((size_t)NN * 128 * 4);
  int*   deg      = (int*)alloc((size_t)NN * 4);
  float* dinv     = (float*)alloc((size_t)NN * 4);
  int*   offs     = (int*)alloc((size_t)NN * 4);
  int*   cursor   = (int*)alloc((size_t)NN * 4);
  int*   bsum     = (int*)alloc(512 * 4);
  int*   csr_src  = (int*)alloc((size_t)NE * 4);
  float* csr_norm = (float*)alloc((size_t)NE * 4);
  float* g        = (float*)alloc((size_t)NG * 128 * 4);
  float* t1       = (float*)alloc((size_t)NG * 128 * 4);

  hipMemsetAsync(deg, 0, (size_t)NN * 4, stream);
  hipMemsetAsync(cursor, 0, (size_t)NN * 4, stream);

  int nbN = (NN + 255) / 256;   // 391
  int nbE = (NE + 255) / 256;   // 6250
  k_deg<<<nbE, 256, 0, stream>>>(dst, deg);
  k_dinv<<<nbN, 256, 0, stream>>>(deg, dinv);
  k_bsum<<<nbN, 256, 0, stream>>>(deg, bsum);
  k_scan_bsum<<<1, 64, 0, stream>>>(bsum, nbN);
  k_offs<<<nbN, 256, 0, stream>>>(deg, bsum, offs);
  k_csr<<<nbE, 256, 0, stream>>>(src, dst, offs, cursor, dinv, csr_src, csr_norm);

  int gM = (NN + 127) / 128;    // 782
  k_gemm<<<gM, 256, 0, stream>>>(x, W_enc, b_enc, h, NN, 1, 0);

  const float* Ws[3] = {W1, W2, W3};
  const float* bs[3] = {b1, b2, b3};
  for (int L = 0; L < 3; ++L) {
    k_gemm<<<gM, 256, 0, stream>>>(h, Ws[L], nullptr, hp, NN, 0, 0);
    k_agg<<<(NN + 3) / 4, 256, 0, stream>>>(hp, offs, deg, dinv, csr_src, csr_norm, bs[L], h, 1);
  }

  k_pool<<<NG, 128, 0, stream>>>(h, batch, g);
  k_gemm<<<(NG + 127) / 128, 256, 0, stream>>>(g, Wr1, br1, t1, NG, 1, 1);
  k_cls<<<NG, 128, 0, stream>>>(t1, Wr2, br2, out);
}

// Round 2
// 605.498 us; speedup vs baseline: 1.7516x; 1.7516x over previous
//
#include <hip/hip_runtime.h>
#include <hip/hip_bf16.h>

#define NN 100000
#define NE 1600000
#define NG 512
#define NC 10

typedef __attribute__((ext_vector_type(8))) short bf16x8;
typedef __attribute__((ext_vector_type(4))) float f32x4;

__device__ __forceinline__ float bflo(unsigned u) { return __uint_as_float(u << 16); }
__device__ __forceinline__ float bfhi(unsigned u) { return __uint_as_float(u & 0xffff0000u); }
__device__ __forceinline__ unsigned short f2bf(float f) {
  unsigned u = __float_as_uint(f);
  unsigned r = u + 0x7fffu + ((u >> 16) & 1u);
  return (unsigned short)(r >> 16);
}

// ---------------- preprocessing: degree, dinv, CSR by dst ----------------

__global__ __launch_bounds__(256) void k_deg(const int* __restrict__ dst, int* __restrict__ deg) {
  int e = blockIdx.x * 256 + threadIdx.x;
  if (e < NE) atomicAdd(&deg[dst[e]], 1);
}

__global__ __launch_bounds__(256) void k_dinv(const int* __restrict__ deg, float* __restrict__ dinv) {
  int i = blockIdx.x * 256 + threadIdx.x;
  if (i < NN) dinv[i] = rsqrtf((float)deg[i] + 1.0f);
}

__global__ __launch_bounds__(256) void k_bsum(const int* __restrict__ deg, int* __restrict__ bsum) {
  __shared__ int sm[256];
  int i = blockIdx.x * 256 + threadIdx.x;
  sm[threadIdx.x] = (i < NN) ? deg[i] : 0;
  __syncthreads();
  for (int o = 128; o > 0; o >>= 1) {
    if (threadIdx.x < o) sm[threadIdx.x] += sm[threadIdx.x + o];
    __syncthreads();
  }
  if (threadIdx.x == 0) bsum[blockIdx.x] = sm[0];
}

__global__ void k_scan_bsum(int* bsum, int nb) {
  if (threadIdx.x == 0 && blockIdx.x == 0) {
    int run = 0;
    for (int b = 0; b < nb; ++b) { int v = bsum[b]; bsum[b] = run; run += v; }
  }
}

__global__ __launch_bounds__(256) void k_offs(const int* __restrict__ deg, const int* __restrict__ bsum,
                                              int* __restrict__ offs) {
  __shared__ int sm[256];
  int i = blockIdx.x * 256 + threadIdx.x;
  int v = (i < NN) ? deg[i] : 0;
  sm[threadIdx.x] = v;
  __syncthreads();
  for (int o = 1; o < 256; o <<= 1) {
    int t = (threadIdx.x >= o) ? sm[threadIdx.x - o] : 0;
    __syncthreads();
    sm[threadIdx.x] += t;
    __syncthreads();
  }
  if (i < NN) offs[i] = bsum[blockIdx.x] + sm[threadIdx.x] - v;  // exclusive
}

__global__ __launch_bounds__(256) void k_csr(const int* __restrict__ src, const int* __restrict__ dst,
                                             const int* __restrict__ offs, int* __restrict__ cursor,
                                             const float* __restrict__ dinv,
                                             int* __restrict__ csr_src, float* __restrict__ csr_norm) {
  int e = blockIdx.x * 256 + threadIdx.x;
  if (e < NE) {
    int s = src[e], d = dst[e];
    int p = offs[d] + atomicAdd(&cursor[d], 1);
    csr_src[p] = s;
    csr_norm[p] = dinv[s] * dinv[d];
  }
}

// ---------------- converts ----------------

__global__ __launch_bounds__(256) void k_f2b(const float* __restrict__ in, unsigned short* __restrict__ out, int n4) {
  for (int i = blockIdx.x * 256 + threadIdx.x; i < n4; i += gridDim.x * 256) {
    float4 v = ((const float4*)in)[i];
    uint2 o;
    o.x = (unsigned)f2bf(v.x) | ((unsigned)f2bf(v.y) << 16);
    o.y = (unsigned)f2bf(v.z) | ((unsigned)f2bf(v.w) << 16);
    ((uint2*)out)[i] = o;
  }
}

// Wt[c][k] = bf16(W[k][c])  (128x128)
__global__ __launch_bounds__(256) void k_wt(const float* __restrict__ W, unsigned short* __restrict__ Wt) {
  int idx = blockIdx.x * 256 + threadIdx.x;
  int k = idx >> 7, c = idx & 127;
  Wt[c * 128 + k] = f2bf(W[k * 128 + c]);
}

// ---------------- bf16 MFMA GEMM: Out[M,128] = A[M,128] @ W[128,128] ----------------
// A bf16 row-major, Wt bf16 = W^T row-major. 256 thr, 128-row tile, 2x2 waves of 64x64.
// LDS: A-tile + Wt in 16B chunks, chunk XOR-swizzled by (row&15) for conflict-free ds_read_b128.

template<int ADD_BIAS, int RELU>
__global__ __launch_bounds__(256) void k_gemm_mfma(const unsigned short* __restrict__ A,
                                                   const unsigned short* __restrict__ Wt,
                                                   const float* __restrict__ bias,
                                                   unsigned short* __restrict__ Out, int M) {
  __shared__ uint4 Al4[2048];  // 128 rows x 16 chunks (16B = 8 bf16)
  __shared__ uint4 Wl4[2048];
  int row0 = blockIdx.x * 128;
  const uint4* A16 = (const uint4*)A;
  const uint4* W16 = (const uint4*)Wt;
#pragma unroll
  for (int it = 0; it < 8; ++it) {
    int idx = it * 256 + threadIdx.x;
    int r = idx >> 4, c = idx & 15;
    int gr = row0 + r;
    uint4 v = make_uint4(0, 0, 0, 0);
    if (gr < M) v = A16[(size_t)gr * 16 + c];
    Al4[r * 16 + (c ^ (r & 15))] = v;
    Wl4[r * 16 + (c ^ (r & 15))] = W16[idx];
  }
  __syncthreads();

  int lane = threadIdx.x & 63;
  int wid = threadIdx.x >> 6;
  int wr = wid >> 1, wc = wid & 1;
  int lr = lane & 15, kb = lane >> 4;

  f32x4 acc[4][4] = {};
#pragma unroll
  for (int ks = 0; ks < 4; ++ks) {
    int c = ks * 4 + kb;
    bf16x8 af[4], bfr[4];
#pragma unroll
    for (int i = 0; i < 4; ++i) {
      int ar = wr * 64 + i * 16 + lr;
      af[i] = *(const bf16x8*)&Al4[ar * 16 + (c ^ lr)];
      int bc = wc * 64 + i * 16 + lr;
      bfr[i] = *(const bf16x8*)&Wl4[bc * 16 + (c ^ lr)];
    }
#pragma unroll
    for (int i = 0; i < 4; ++i)
#pragma unroll
      for (int n = 0; n < 4; ++n)
        acc[i][n] = __builtin_amdgcn_mfma_f32_16x16x32_bf16(af[i], bfr[n], acc[i][n], 0, 0, 0);
  }

  float bcol[4];
  if (ADD_BIAS) {
#pragma unroll
    for (int n = 0; n < 4; ++n) bcol[n] = bias[wc * 64 + n * 16 + lr];
  }
#pragma unroll
  for (int i = 0; i < 4; ++i) {
    int rbase = row0 + wr * 64 + i * 16 + kb * 4;
#pragma unroll
    for (int n = 0; n < 4; ++n) {
      int col = wc * 64 + n * 16 + lr;
#pragma unroll
      for (int j = 0; j < 4; ++j) {
        int gr = rbase + j;
        if (gr < M) {
          float v = acc[i][n][j];
          if (ADD_BIAS) v += bcol[n];
          if (RELU) v = fmaxf(v, 0.f);
          Out[(size_t)gr * 128 + col] = f2bf(v);
        }
      }
    }
  }
}

// ---------------- edge aggregation (bf16 gather, f32 accum, bf16 out) ----------------
// out[i,:] = relu( sum_{e:dst=i} hp[src]*norm + hp[i]*dinv_i^2 + b )

__global__ __launch_bounds__(256) void k_agg(const unsigned short* __restrict__ hp,
                                             const int* __restrict__ offs, const int* __restrict__ deg,
                                             const float* __restrict__ dinv,
                                             const int* __restrict__ csr_src, const float* __restrict__ csr_norm,
                                             const float* __restrict__ bias,
                                             unsigned short* __restrict__ out) {
  int node = blockIdx.x * 4 + (threadIdx.x >> 6);
  if (node >= NN) return;
  int l = threadIdx.x & 63;
  const unsigned* hp32 = (const unsigned*)hp;  // 64 u32 per row
  float di = dinv[node];
  unsigned v = hp32[node * 64 + l];
  float ax = bflo(v) * di * di, ay = bfhi(v) * di * di;
  int p0 = offs[node], n = deg[node];
  int p = 0;
  for (; p + 4 <= n; p += 4) {
    int s0 = csr_src[p0 + p], s1 = csr_src[p0 + p + 1], s2 = csr_src[p0 + p + 2], s3 = csr_src[p0 + p + 3];
    float w0 = csr_norm[p0 + p], w1 = csr_norm[p0 + p + 1], w2 = csr_norm[p0 + p + 2], w3 = csr_norm[p0 + p + 3];
    unsigned u0 = hp32[s0 * 64 + l], u1 = hp32[s1 * 64 + l], u2 = hp32[s2 * 64 + l], u3 = hp32[s3 * 64 + l];
    ax += bflo(u0) * w0 + bflo(u1) * w1 + bflo(u2) * w2 + bflo(u3) * w3;
    ay += bfhi(u0) * w0 + bfhi(u1) * w1 + bfhi(u2) * w2 + bfhi(u3) * w3;
  }
  for (; p < n; ++p) {
    int s0 = csr_src[p0 + p];
    float w0 = csr_norm[p0 + p];
    unsigned u0 = hp32[s0 * 64 + l];
    ax += bflo(u0) * w0;
    ay += bfhi(u0) * w0;
  }
  float2 b2 = ((const float2*)bias)[l];
  ax = fmaxf(ax + b2.x, 0.f);
  ay = fmaxf(ay + b2.y, 0.f);
  ((unsigned*)out)[node * 64 + l] = (unsigned)f2bf(ax) | ((unsigned)f2bf(ay) << 16);
}

// ---------------- pooling over sorted batch + small MLP ----------------

__device__ __forceinline__ int lowerb(const int* a, int n, int key) {
  int lo = 0, hi = n;
  while (lo < hi) {
    int mid = (lo + hi) >> 1;
    if (a[mid] < key) lo = mid + 1; else hi = mid;
  }
  return lo;
}

__global__ __launch_bounds__(128) void k_pool(const unsigned short* __restrict__ h, const int* __restrict__ batch,
                                              float* __restrict__ g) {
  int gi = blockIdx.x, d = threadIdx.x;
  int lo = lowerb(batch, NN, gi), hi = lowerb(batch, NN, gi + 1);
  float acc = 0.f;
  for (int i = lo; i < hi; ++i) acc += bflo((unsigned)h[i * 128 + d]);
  g[gi * 128 + d] = acc;
}

// small f32 GEMM for t1 = relu(g @ Wr1 + br1): M=512
__global__ __launch_bounds__(256) void k_gemm_f32(const float* __restrict__ A, const float* __restrict__ W,
                                                  const float* __restrict__ bias, float* __restrict__ Out,
                                                  int M) {
  __shared__ float4 Wl[128 * 32];
  __shared__ float4 Xl[128 * 32];
  const float4* W4 = (const float4*)W;
  for (int i = threadIdx.x; i < 4096; i += 256) Wl[i] = W4[i];
  int row0 = blockIdx.x * 128;
  const float4* A4 = (const float4*)A;
  for (int i = threadIdx.x; i < 4096; i += 256) {
    int r = i >> 5, g = i & 31;
    int gr = row0 + r;
    float4 v = make_float4(0.f, 0.f, 0.f, 0.f);
    if (gr < M) v = A4[gr * 32 + g];
    Xl[r * 32 + (g ^ ((r >> 3) & 7))] = v;
  }
  __syncthreads();

  int cg = threadIdx.x & 15;
  int rg = threadIdx.x >> 4;
  int swz = rg & 7;
  float acc[8][8] = {};
  for (int g = 0; g < 32; ++g) {
    float4 xv[8];
#pragma unroll
    for (int i = 0; i < 8; ++i) xv[i] = Xl[(rg * 8 + i) * 32 + (g ^ swz)];
#pragma unroll
    for (int kk = 0; kk < 4; ++kk) {
      float4 wa = Wl[(g * 4 + kk) * 32 + cg * 2];
      float4 wb = Wl[(g * 4 + kk) * 32 + cg * 2 + 1];
#pragma unroll
      for (int i = 0; i < 8; ++i) {
        float x = (kk == 0) ? xv[i].x : (kk == 1) ? xv[i].y : (kk == 2) ? xv[i].z : xv[i].w;
        acc[i][0] = fmaf(x, wa.x, acc[i][0]);
        acc[i][1] = fmaf(x, wa.y, acc[i][1]);
        acc[i][2] = fmaf(x, wa.z, acc[i][2]);
        acc[i][3] = fmaf(x, wa.w, acc[i][3]);
        acc[i][4] = fmaf(x, wb.x, acc[i][4]);
        acc[i][5] = fmaf(x, wb.y, acc[i][5]);
        acc[i][6] = fmaf(x, wb.z, acc[i][6]);
        acc[i][7] = fmaf(x, wb.w, acc[i][7]);
      }
    }
  }
  float4 ba = ((const float4*)bias)[cg * 2];
  float4 bb = ((const float4*)bias)[cg * 2 + 1];
#pragma unroll
  for (int i = 0; i < 8; ++i) {
    int gr = row0 + rg * 8 + i;
    if (gr < M) {
      float4 oa, ob;
      oa.x = fmaxf(acc[i][0] + ba.x, 0.f); oa.y = fmaxf(acc[i][1] + ba.y, 0.f);
      oa.z = fmaxf(acc[i][2] + ba.z, 0.f); oa.w = fmaxf(acc[i][3] + ba.w, 0.f);
      ob.x = fmaxf(acc[i][4] + bb.x, 0.f); ob.y = fmaxf(acc[i][5] + bb.y, 0.f);
      ob.z = fmaxf(acc[i][6] + bb.z, 0.f); ob.w = fmaxf(acc[i][7] + bb.w, 0.f);
      ((float4*)Out)[gr * 32 + cg * 2] = oa;
      ((float4*)Out)[gr * 32 + cg * 2 + 1] = ob;
    }
  }
}

__global__ __launch_bounds__(128) void k_cls(const float* __restrict__ t, const float* __restrict__ Wr2,
                                             const float* __restrict__ br2, float* __restrict__ out) {
  int gi = blockIdx.x;
  __shared__ float row[128];
  row[threadIdx.x] = t[gi * 128 + threadIdx.x];
  __syncthreads();
  if (threadIdx.x < NC) {
    float acc = br2[threadIdx.x];
    for (int k = 0; k < 128; ++k) acc = fmaf(row[k], Wr2[k * NC + threadIdx.x], acc);
    out[gi * NC + threadIdx.x] = acc;
  }
}

// ---------------- launch ----------------

extern "C" void kernel_launch(void* const* d_in, const int* in_sizes, int n_in,
                              void* d_out, int out_size, void* d_ws, size_t ws_size,
                              hipStream_t stream) {
  const float* x     = (const float*)d_in[0];
  const int*   src   = (const int*)d_in[1];
  const int*   dst   = (const int*)d_in[2];
  const int*   batch = (const int*)d_in[3];
  const float* W_enc = (const float*)d_in[4];
  const float* b_enc = (const float*)d_in[5];
  const float* W1 = (const float*)d_in[6],  *b1 = (const float*)d_in[7];
  const float* W2 = (const float*)d_in[8],  *b2 = (const float*)d_in[9];
  const float* W3 = (const float*)d_in[10], *b3 = (const float*)d_in[11];
  const float* Wr1 = (const float*)d_in[12], *br1 = (const float*)d_in[13];
  const float* Wr2 = (const float*)d_in[14], *br2 = (const float*)d_in[15];
  float* out = (float*)d_out;

  char* ws = (char*)d_ws;
  size_t off = 0;
  auto alloc = [&](size_t bytes) {
    void* p = ws + off;
    off = (off + bytes + 255) & ~(size_t)255;
    return p;
  };
  unsigned short* xb  = (unsigned short*)alloc((size_t)NN * 128 * 2);
  unsigned short* h   = (unsigned short*)alloc((size_t)NN * 128 * 2);
  unsigned short* hp  = (unsigned short*)alloc((size_t)NN * 128 * 2);
  unsigned short* WtE = (unsigned short*)alloc(128 * 128 * 2);
  unsigned short* Wt1 = (unsigned short*)alloc(128 * 128 * 2);
  unsigned short* Wt2 = (unsigned short*)alloc(128 * 128 * 2);
  unsigned short* Wt3 = (unsigned short*)alloc(128 * 128 * 2);
  int*   deg      = (int*)alloc((size_t)NN * 4);
  float* dinv     = (float*)alloc((size_t)NN * 4);
  int*   offs     = (int*)alloc((size_t)NN * 4);
  int*   cursor   = (int*)alloc((size_t)NN * 4);
  int*   bsum     = (int*)alloc(512 * 4);
  int*   csr_src  = (int*)alloc((size_t)NE * 4);
  float* csr_norm = (float*)alloc((size_t)NE * 4);
  float* g        = (float*)alloc((size_t)NG * 128 * 4);
  float* t1       = (float*)alloc((size_t)NG * 128 * 4);

  hipMemsetAsync(deg, 0, (size_t)NN * 4, stream);
  hipMemsetAsync(cursor, 0, (size_t)NN * 4, stream);

  int nbN = (NN + 255) / 256;
  int nbE = (NE + 255) / 256;
  k_deg<<<nbE, 256, 0, stream>>>(dst, deg);
  k_dinv<<<nbN, 256, 0, stream>>>(deg, dinv);
  k_bsum<<<nbN, 256, 0, stream>>>(deg, bsum);
  k_scan_bsum<<<1, 64, 0, stream>>>(bsum, nbN);
  k_offs<<<nbN, 256, 0, stream>>>(deg, bsum, offs);
  k_csr<<<nbE, 256, 0, stream>>>(src, dst, offs, cursor, dinv, csr_src, csr_norm);

  k_f2b<<<2048, 256, 0, stream>>>(x, xb, NN * 128 / 4);
  k_wt<<<64, 256, 0, stream>>>(W_enc, WtE);
  k_wt<<<64, 256, 0, stream>>>(W1, Wt1);
  k_wt<<<64, 256, 0, stream>>>(W2, Wt2);
  k_wt<<<64, 256, 0, stream>>>(W3, Wt3);

  int gM = (NN + 127) / 128;  // 782
  k_gemm_mfma<1, 0><<<gM, 256, 0, stream>>>(xb, WtE, b_enc, h, NN);

  const unsigned short* Wts[3] = {Wt1, Wt2, Wt3};
  const float* bs[3] = {b1, b2, b3};
  for (int L = 0; L < 3; ++L) {
    k_gemm_mfma<0, 0><<<gM, 256, 0, stream>>>(h, Wts[L], nullptr, hp, NN);
    k_agg<<<(NN + 3) / 4, 256, 0, stream>>>(hp, offs, deg, dinv, csr_src, csr_norm, bs[L], h);
  }

  k_pool<<<NG, 128, 0, stream>>>(h, batch, g);
  k_gemm_f32<<<(NG + 127) / 128, 256, 0, stream>>>(g, Wr1, br1, t1, NG);
  k_cls<<<NG, 128, 0, stream>>>(t1, Wr2, br2, out);
}

// Round 3
// 563.553 us; speedup vs baseline: 1.8820x; 1.0744x over previous
//
#include <hip/hip_runtime.h>
#include <hip/hip_bf16.h>

#define NN 100000
#define NE 1600000
#define NG 512
#define NC 10

typedef __attribute__((ext_vector_type(8))) short bf16x8;
typedef __attribute__((ext_vector_type(4))) float f32x4;

__device__ __forceinline__ float bflo(unsigned u) { return __uint_as_float(u << 16); }
__device__ __forceinline__ float bfhi(unsigned u) { return __uint_as_float(u & 0xffff0000u); }
__device__ __forceinline__ unsigned short f2bf(float f) {
  unsigned u = __float_as_uint(f);
  unsigned r = u + 0x7fffu + ((u >> 16) & 1u);
  return (unsigned short)(r >> 16);
}

// ---------------- preprocessing: degree, dinv, CSR (AoS) by dst ----------------

__global__ __launch_bounds__(256) void k_deg(const int* __restrict__ dst, int* __restrict__ deg) {
  int e = blockIdx.x * 256 + threadIdx.x;
  if (e < NE) atomicAdd(&deg[dst[e]], 1);
}

__global__ __launch_bounds__(256) void k_dinv(const int* __restrict__ deg, float* __restrict__ dinv) {
  int i = blockIdx.x * 256 + threadIdx.x;
  if (i < NN) dinv[i] = rsqrtf((float)deg[i] + 1.0f);
}

__global__ __launch_bounds__(256) void k_bsum(const int* __restrict__ deg, int* __restrict__ bsum) {
  __shared__ int sm[256];
  int i = blockIdx.x * 256 + threadIdx.x;
  sm[threadIdx.x] = (i < NN) ? deg[i] : 0;
  __syncthreads();
  for (int o = 128; o > 0; o >>= 1) {
    if (threadIdx.x < o) sm[threadIdx.x] += sm[threadIdx.x + o];
    __syncthreads();
  }
  if (threadIdx.x == 0) bsum[blockIdx.x] = sm[0];
}

// parallel exclusive scan of bsum (nb <= 512), one block of 512 threads
__global__ __launch_bounds__(512) void k_scan_par(int* bsum, int nb) {
  __shared__ int sm[512];
  int t = threadIdx.x;
  int orig = (t < nb) ? bsum[t] : 0;
  sm[t] = orig;
  __syncthreads();
  for (int o = 1; o < 512; o <<= 1) {
    int v = (t >= o) ? sm[t - o] : 0;
    __syncthreads();
    sm[t] += v;
    __syncthreads();
  }
  if (t < nb) bsum[t] = sm[t] - orig;  // exclusive
}

__global__ __launch_bounds__(256) void k_offs(const int* __restrict__ deg, const int* __restrict__ bsum,
                                              int* __restrict__ offs) {
  __shared__ int sm[256];
  int i = blockIdx.x * 256 + threadIdx.x;
  int v = (i < NN) ? deg[i] : 0;
  sm[threadIdx.x] = v;
  __syncthreads();
  for (int o = 1; o < 256; o <<= 1) {
    int t = (threadIdx.x >= o) ? sm[threadIdx.x - o] : 0;
    __syncthreads();
    sm[threadIdx.x] += t;
    __syncthreads();
  }
  if (i < NN) offs[i] = bsum[blockIdx.x] + sm[threadIdx.x] - v;  // exclusive
}

__global__ __launch_bounds__(256) void k_csr(const int* __restrict__ src, const int* __restrict__ dst,
                                             const int* __restrict__ offs, int* __restrict__ cursor,
                                             const float* __restrict__ dinv,
                                             int2* __restrict__ csr) {
  int e = blockIdx.x * 256 + threadIdx.x;
  if (e < NE) {
    int s = src[e], d = dst[e];
    int p = offs[d] + atomicAdd(&cursor[d], 1);
    int2 v;
    v.x = s;
    v.y = __float_as_int(dinv[s] * dinv[d]);
    csr[p] = v;
  }
}

// Wt[c][k] = bf16(W[k][c])  (128x128)
__global__ __launch_bounds__(256) void k_wt(const float* __restrict__ W, unsigned short* __restrict__ Wt) {
  int idx = blockIdx.x * 256 + threadIdx.x;
  int k = idx >> 7, c = idx & 127;
  Wt[c * 128 + k] = f2bf(W[k * 128 + c]);
}

// ---------------- bf16 MFMA GEMM: Out[M,128] = A[M,128] @ W[128,128] ----------------
// A bf16 (or f32, converted at stage time), Wt = W^T bf16 row-major.
// 256 thr, 128-row tile, 2x2 waves of 64x64; 16B-chunk XOR swizzle for conflict-free ds_read_b128.

template<int ADD_BIAS, int RELU, int SRC_F32>
__global__ __launch_bounds__(256) void k_gemm_mfma(const void* __restrict__ Ap,
                                                   const unsigned short* __restrict__ Wt,
                                                   const float* __restrict__ bias,
                                                   unsigned short* __restrict__ Out, int M) {
  __shared__ uint4 Al4[2048];  // 128 rows x 16 chunks (16B = 8 bf16)
  __shared__ uint4 Wl4[2048];
  int row0 = blockIdx.x * 128;
  const uint4* W16 = (const uint4*)Wt;
#pragma unroll
  for (int it = 0; it < 8; ++it) {
    int idx = it * 256 + threadIdx.x;
    int r = idx >> 4, c = idx & 15;
    int gr = row0 + r;
    uint4 v = make_uint4(0, 0, 0, 0);
    if (gr < M) {
      if (SRC_F32) {
        const float4* Af = (const float4*)Ap;
        float4 f0 = Af[(size_t)gr * 32 + c * 2];
        float4 f1 = Af[(size_t)gr * 32 + c * 2 + 1];
        v.x = (unsigned)f2bf(f0.x) | ((unsigned)f2bf(f0.y) << 16);
        v.y = (unsigned)f2bf(f0.z) | ((unsigned)f2bf(f0.w) << 16);
        v.z = (unsigned)f2bf(f1.x) | ((unsigned)f2bf(f1.y) << 16);
        v.w = (unsigned)f2bf(f1.z) | ((unsigned)f2bf(f1.w) << 16);
      } else {
        v = ((const uint4*)Ap)[(size_t)gr * 16 + c];
      }
    }
    Al4[r * 16 + (c ^ (r & 15))] = v;
    Wl4[r * 16 + (c ^ (r & 15))] = W16[idx];
  }
  __syncthreads();

  int lane = threadIdx.x & 63;
  int wid = threadIdx.x >> 6;
  int wr = wid >> 1, wc = wid & 1;
  int lr = lane & 15, kb = lane >> 4;

  f32x4 acc[4][4] = {};
#pragma unroll
  for (int ks = 0; ks < 4; ++ks) {
    int c = ks * 4 + kb;
    bf16x8 af[4], bfr[4];
#pragma unroll
    for (int i = 0; i < 4; ++i) {
      int ar = wr * 64 + i * 16 + lr;
      af[i] = *(const bf16x8*)&Al4[ar * 16 + (c ^ lr)];
      int bc = wc * 64 + i * 16 + lr;
      bfr[i] = *(const bf16x8*)&Wl4[bc * 16 + (c ^ lr)];
    }
#pragma unroll
    for (int i = 0; i < 4; ++i)
#pragma unroll
      for (int n = 0; n < 4; ++n)
        acc[i][n] = __builtin_amdgcn_mfma_f32_16x16x32_bf16(af[i], bfr[n], acc[i][n], 0, 0, 0);
  }

  float bcol[4];
  if (ADD_BIAS) {
#pragma unroll
    for (int n = 0; n < 4; ++n) bcol[n] = bias[wc * 64 + n * 16 + lr];
  }
#pragma unroll
  for (int i = 0; i < 4; ++i) {
    int rbase = row0 + wr * 64 + i * 16 + kb * 4;
#pragma unroll
    for (int n = 0; n < 4; ++n) {
      int col = wc * 64 + n * 16 + lr;
#pragma unroll
      for (int j = 0; j < 4; ++j) {
        int gr = rbase + j;
        if (gr < M) {
          float v = acc[i][n][j];
          if (ADD_BIAS) v += bcol[n];
          if (RELU) v = fmaxf(v, 0.f);
          Out[(size_t)gr * 128 + col] = f2bf(v);
        }
      }
    }
  }
}

// ---------------- edge aggregation (bf16 gather, f32 accum, bf16 out) ----------------
// out[i,:] = relu( sum_{e:dst=i} hp[src]*norm + hp[i]*dinv_i^2 + b )

__global__ __launch_bounds__(256) void k_agg(const unsigned short* __restrict__ hp,
                                             const int* __restrict__ offs, const int* __restrict__ deg,
                                             const float* __restrict__ dinv,
                                             const int2* __restrict__ csr,
                                             const float* __restrict__ bias,
                                             unsigned short* __restrict__ out) {
  int node = blockIdx.x * 4 + (threadIdx.x >> 6);
  if (node >= NN) return;
  int l = threadIdx.x & 63;
  const unsigned* hp32 = (const unsigned*)hp;  // 64 u32 per row
  float di = dinv[node];
  unsigned v = hp32[node * 64 + l];
  float ax = bflo(v) * di * di, ay = bfhi(v) * di * di;
  int p0 = offs[node], n = deg[node];
  int p = 0;
  for (; p + 8 <= n; p += 8) {
    int2 e0 = csr[p0 + p], e1 = csr[p0 + p + 1], e2 = csr[p0 + p + 2], e3 = csr[p0 + p + 3];
    int2 e4 = csr[p0 + p + 4], e5 = csr[p0 + p + 5], e6 = csr[p0 + p + 6], e7 = csr[p0 + p + 7];
    unsigned u0 = hp32[e0.x * 64 + l], u1 = hp32[e1.x * 64 + l];
    unsigned u2 = hp32[e2.x * 64 + l], u3 = hp32[e3.x * 64 + l];
    unsigned u4 = hp32[e4.x * 64 + l], u5 = hp32[e5.x * 64 + l];
    unsigned u6 = hp32[e6.x * 64 + l], u7 = hp32[e7.x * 64 + l];
    float w0 = __int_as_float(e0.y), w1 = __int_as_float(e1.y), w2 = __int_as_float(e2.y), w3 = __int_as_float(e3.y);
    float w4 = __int_as_float(e4.y), w5 = __int_as_float(e5.y), w6 = __int_as_float(e6.y), w7 = __int_as_float(e7.y);
    ax += bflo(u0) * w0 + bflo(u1) * w1 + bflo(u2) * w2 + bflo(u3) * w3
        + bflo(u4) * w4 + bflo(u5) * w5 + bflo(u6) * w6 + bflo(u7) * w7;
    ay += bfhi(u0) * w0 + bfhi(u1) * w1 + bfhi(u2) * w2 + bfhi(u3) * w3
        + bfhi(u4) * w4 + bfhi(u5) * w5 + bfhi(u6) * w6 + bfhi(u7) * w7;
  }
  for (; p < n; ++p) {
    int2 e0 = csr[p0 + p];
    unsigned u0 = hp32[e0.x * 64 + l];
    float w0 = __int_as_float(e0.y);
    ax += bflo(u0) * w0;
    ay += bfhi(u0) * w0;
  }
  float2 b2 = ((const float2*)bias)[l];
  ax = fmaxf(ax + b2.x, 0.f);
  ay = fmaxf(ay + b2.y, 0.f);
  ((unsigned*)out)[node * 64 + l] = (unsigned)f2bf(ax) | ((unsigned)f2bf(ay) << 16);
}

// ---------------- pooling over sorted batch + small MLP ----------------

__device__ __forceinline__ int lowerb(const int* a, int n, int key) {
  int lo = 0, hi = n;
  while (lo < hi) {
    int mid = (lo + hi) >> 1;
    if (a[mid] < key) lo = mid + 1; else hi = mid;
  }
  return lo;
}

__global__ __launch_bounds__(128) void k_pool(const unsigned short* __restrict__ h, const int* __restrict__ batch,
                                              float* __restrict__ g) {
  int gi = blockIdx.x, d = threadIdx.x;
  int lo = lowerb(batch, NN, gi), hi = lowerb(batch, NN, gi + 1);
  float acc = 0.f;
  for (int i = lo; i < hi; ++i) acc += bflo((unsigned)h[i * 128 + d]);
  g[gi * 128 + d] = acc;
}

// small f32 GEMM for t1 = relu(g @ Wr1 + br1): M=512
__global__ __launch_bounds__(256) void k_gemm_f32(const float* __restrict__ A, const float* __restrict__ W,
                                                  const float* __restrict__ bias, float* __restrict__ Out,
                                                  int M) {
  __shared__ float4 Wl[128 * 32];
  __shared__ float4 Xl[128 * 32];
  const float4* W4 = (const float4*)W;
  for (int i = threadIdx.x; i < 4096; i += 256) Wl[i] = W4[i];
  int row0 = blockIdx.x * 128;
  const float4* A4 = (const float4*)A;
  for (int i = threadIdx.x; i < 4096; i += 256) {
    int r = i >> 5, g = i & 31;
    int gr = row0 + r;
    float4 v = make_float4(0.f, 0.f, 0.f, 0.f);
    if (gr < M) v = A4[gr * 32 + g];
    Xl[r * 32 + (g ^ ((r >> 3) & 7))] = v;
  }
  __syncthreads();

  int cg = threadIdx.x & 15;
  int rg = threadIdx.x >> 4;
  int swz = rg & 7;
  float acc[8][8] = {};
  for (int g = 0; g < 32; ++g) {
    float4 xv[8];
#pragma unroll
    for (int i = 0; i < 8; ++i) xv[i] = Xl[(rg * 8 + i) * 32 + (g ^ swz)];
#pragma unroll
    for (int kk = 0; kk < 4; ++kk) {
      float4 wa = Wl[(g * 4 + kk) * 32 + cg * 2];
      float4 wb = Wl[(g * 4 + kk) * 32 + cg * 2 + 1];
#pragma unroll
      for (int i = 0; i < 8; ++i) {
        float x = (kk == 0) ? xv[i].x : (kk == 1) ? xv[i].y : (kk == 2) ? xv[i].z : xv[i].w;
        acc[i][0] = fmaf(x, wa.x, acc[i][0]);
        acc[i][1] = fmaf(x, wa.y, acc[i][1]);
        acc[i][2] = fmaf(x, wa.z, acc[i][2]);
        acc[i][3] = fmaf(x, wa.w, acc[i][3]);
        acc[i][4] = fmaf(x, wb.x, acc[i][4]);
        acc[i][5] = fmaf(x, wb.y, acc[i][5]);
        acc[i][6] = fmaf(x, wb.z, acc[i][6]);
        acc[i][7] = fmaf(x, wb.w, acc[i][7]);
      }
    }
  }
  float4 ba = ((const float4*)bias)[cg * 2];
  float4 bb = ((const float4*)bias)[cg * 2 + 1];
#pragma unroll
  for (int i = 0; i < 8; ++i) {
    int gr = row0 + rg * 8 + i;
    if (gr < M) {
      float4 oa, ob;
      oa.x = fmaxf(acc[i][0] + ba.x, 0.f); oa.y = fmaxf(acc[i][1] + ba.y, 0.f);
      oa.z = fmaxf(acc[i][2] + ba.z, 0.f); oa.w = fmaxf(acc[i][3] + ba.w, 0.f);
      ob.x = fmaxf(acc[i][4] + bb.x, 0.f); ob.y = fmaxf(acc[i][5] + bb.y, 0.f);
      ob.z = fmaxf(acc[i][6] + bb.z, 0.f); ob.w = fmaxf(acc[i][7] + bb.w, 0.f);
      ((float4*)Out)[gr * 32 + cg * 2] = oa;
      ((float4*)Out)[gr * 32 + cg * 2 + 1] = ob;
    }
  }
}

__global__ __launch_bounds__(128) void k_cls(const float* __restrict__ t, const float* __restrict__ Wr2,
                                             const float* __restrict__ br2, float* __restrict__ out) {
  int gi = blockIdx.x;
  __shared__ float row[128];
  row[threadIdx.x] = t[gi * 128 + threadIdx.x];
  __syncthreads();
  if (threadIdx.x < NC) {
    float acc = br2[threadIdx.x];
    for (int k = 0; k < 128; ++k) acc = fmaf(row[k], Wr2[k * NC + threadIdx.x], acc);
    out[gi * NC + threadIdx.x] = acc;
  }
}

// ---------------- launch ----------------

extern "C" void kernel_launch(void* const* d_in, const int* in_sizes, int n_in,
                              void* d_out, int out_size, void* d_ws, size_t ws_size,
                              hipStream_t stream) {
  const float* x     = (const float*)d_in[0];
  const int*   src   = (const int*)d_in[1];
  const int*   dst   = (const int*)d_in[2];
  const int*   batch = (const int*)d_in[3];
  const float* W_enc = (const float*)d_in[4];
  const float* b_enc = (const float*)d_in[5];
  const float* W1 = (const float*)d_in[6],  *b1 = (const float*)d_in[7];
  const float* W2 = (const float*)d_in[8],  *b2 = (const float*)d_in[9];
  const float* W3 = (const float*)d_in[10], *b3 = (const float*)d_in[11];
  const float* Wr1 = (const float*)d_in[12], *br1 = (const float*)d_in[13];
  const float* Wr2 = (const float*)d_in[14], *br2 = (const float*)d_in[15];
  float* out = (float*)d_out;

  char* ws = (char*)d_ws;
  size_t off = 0;
  auto alloc = [&](size_t bytes) {
    void* p = ws + off;
    off = (off + bytes + 255) & ~(size_t)255;
    return p;
  };
  unsigned short* h   = (unsigned short*)alloc((size_t)NN * 128 * 2);
  unsigned short* hp  = (unsigned short*)alloc((size_t)NN * 128 * 2);
  unsigned short* WtE = (unsigned short*)alloc(128 * 128 * 2);
  unsigned short* Wt1 = (unsigned short*)alloc(128 * 128 * 2);
  unsigned short* Wt2 = (unsigned short*)alloc(128 * 128 * 2);
  unsigned short* Wt3 = (unsigned short*)alloc(128 * 128 * 2);
  int*   deg      = (int*)alloc((size_t)NN * 4);
  float* dinv     = (float*)alloc((size_t)NN * 4);
  int*   offs     = (int*)alloc((size_t)NN * 4);
  int*   cursor   = (int*)alloc((size_t)NN * 4);
  int*   bsum     = (int*)alloc(512 * 4);
  int2*  csr      = (int2*)alloc((size_t)NE * 8);
  float* g        = (float*)alloc((size_t)NG * 128 * 4);
  float* t1       = (float*)alloc((size_t)NG * 128 * 4);

  hipMemsetAsync(deg, 0, (size_t)NN * 4, stream);
  hipMemsetAsync(cursor, 0, (size_t)NN * 4, stream);

  int nbN = (NN + 255) / 256;   // 391
  int nbE = (NE + 255) / 256;   // 6250
  k_deg<<<nbE, 256, 0, stream>>>(dst, deg);
  k_dinv<<<nbN, 256, 0, stream>>>(deg, dinv);
  k_bsum<<<nbN, 256, 0, stream>>>(deg, bsum);
  k_scan_par<<<1, 512, 0, stream>>>(bsum, nbN);
  k_offs<<<nbN, 256, 0, stream>>>(deg, bsum, offs);
  k_csr<<<nbE, 256, 0, stream>>>(src, dst, offs, cursor, dinv, csr);

  k_wt<<<64, 256, 0, stream>>>(W_enc, WtE);
  k_wt<<<64, 256, 0, stream>>>(W1, Wt1);
  k_wt<<<64, 256, 0, stream>>>(W2, Wt2);
  k_wt<<<64, 256, 0, stream>>>(W3, Wt3);

  int gM = (NN + 127) / 128;  // 782
  k_gemm_mfma<1, 0, 1><<<gM, 256, 0, stream>>>(x, WtE, b_enc, h, NN);

  const unsigned short* Wts[3] = {Wt1, Wt2, Wt3};
  const float* bs[3] = {b1, b2, b3};
  for (int L = 0; L < 3; ++L) {
    k_gemm_mfma<0, 0, 0><<<gM, 256, 0, stream>>>(h, Wts[L], nullptr, hp, NN);
    k_agg<<<(NN + 3) / 4, 256, 0, stream>>>(hp, offs, deg, dinv, csr, bs[L], h);
  }

  k_pool<<<NG, 128, 0, stream>>>(h, batch, g);
  k_gemm_f32<<<(NG + 127) / 128, 256, 0, stream>>>(g, Wr1, br1, t1, NG);
  k_cls<<<NG, 128, 0, stream>>>(t1, Wr2, br2, out);
}